// Round 1
// baseline (221.282 us; speedup 1.0000x reference)
//
#include <hip/hip_runtime.h>

typedef __attribute__((ext_vector_type(8))) short bf16x8;
typedef __attribute__((ext_vector_type(4))) float f32x4;

#define DEV __device__ __forceinline__

static constexpr int N_TOK = 4096;
static constexpr int C     = 528;
static constexpr int NH    = 8;
static constexpr int HD    = 66;
static constexpr int HDP   = 96;    // q/k head-dim padded (K-dim of QK^T MFMA)
static constexpr int VDP   = 80;    // v head-dim padded (N-dim of PV MFMA)
static constexpr int KP    = 544;   // GEMM K padded 528->544 (17*32)
static constexpr int NQKV  = 1584;
static constexpr int NQKVP = 1632;  // 17*96

DEV unsigned short f2bf(float f) {
    unsigned int u = __float_as_uint(f);
    u = (u + 0x7fffu + ((u >> 16) & 1u)) >> 16;
    return (unsigned short)u;
}
DEV float bf2f(unsigned short h) { return __uint_as_float(((unsigned int)h) << 16); }

// ---------------- prep ----------------
__global__ void k_prep_x(const float* __restrict__ x, unsigned short* __restrict__ xb) {
    int idx = blockIdx.x * 256 + threadIdx.x;
    if (idx >= N_TOK * KP) return;
    int n = idx / KP, k = idx - n * KP;
    xb[idx] = (k < C) ? f2bf(x[n * C + k]) : (unsigned short)0;
}
__global__ void k_prep_wqkv(const float* __restrict__ w, unsigned short* __restrict__ wb) {
    int idx = blockIdx.x * 256 + threadIdx.x;
    if (idx >= NQKVP * KP) return;
    int n = idx / KP, k = idx - n * KP;
    wb[idx] = (n < NQKV && k < C) ? f2bf(w[n * C + k]) : (unsigned short)0;
}
__global__ void k_prep_wproj(const float* __restrict__ w, unsigned short* __restrict__ whi,
                             unsigned short* __restrict__ wlo) {
    int idx = blockIdx.x * 256 + threadIdx.x;
    if (idx >= KP * KP) return;
    int n = idx / KP, k = idx - n * KP;
    unsigned short hi = 0, lo = 0;
    if (n < C && k < C) {
        float v = w[n * C + k];
        hi = f2bf(v);
        lo = f2bf(v - bf2f(hi));
    }
    whi[idx] = hi; wlo[idx] = lo;
}
__global__ void k_zero_pads(unsigned short* __restrict__ ahi, unsigned short* __restrict__ alo) {
    int idx = blockIdx.x * 256 + threadIdx.x;
    if (idx >= N_TOK * (KP - C)) return;
    int n = idx >> 4, c = C + (idx & 15);
    ahi[n * KP + c] = 0; alo[n * KP + c] = 0;
}

// ---------------- QKV GEMM: xb[4096][544] @ wqkvb[1632][544]^T -> qkv_tmp[4096][1632] bf16 ----------------
__launch_bounds__(256)
__global__ void k_gemm_qkv(const unsigned short* __restrict__ A,
                           const unsigned short* __restrict__ B,
                           const float* __restrict__ bias,
                           unsigned short* __restrict__ Cout) {
    constexpr int BM = 128, BN = 96, LDA = 40, LDB = 40;
    __shared__ unsigned short Al[BM * LDA];
    __shared__ unsigned short Bl[BN * LDB];
    int tid = threadIdx.x, lane = tid & 63, wid = tid >> 6;
    int m0 = blockIdx.x * BM, n0 = blockIdx.y * BN;
    int wm = (wid >> 1) * 64;   // wave M offset (WM=4 tiles)
    int wn = (wid & 1) * 48;    // wave N offset (WN=3 tiles)
    f32x4 acc[4][3] = {};
    for (int k0 = 0; k0 < KP; k0 += 32) {
        __syncthreads();
#pragma unroll
        for (int i = 0; i < 2; i++) {
            int c = i * 256 + tid;
            int row = c >> 2, kc = (c & 3) * 8;
            *(bf16x8*)&Al[row * LDA + kc] = *(const bf16x8*)&A[(m0 + row) * KP + k0 + kc];
        }
        {
            int c = tid, row = c >> 2, kc = (c & 3) * 8;
            *(bf16x8*)&Bl[row * LDB + kc] = *(const bf16x8*)&B[(n0 + row) * KP + k0 + kc];
            c = 256 + tid;
            if (c < 384) {
                row = c >> 2; kc = (c & 3) * 8;
                *(bf16x8*)&Bl[row * LDB + kc] = *(const bf16x8*)&B[(n0 + row) * KP + k0 + kc];
            }
        }
        __syncthreads();
        int kk = (lane >> 4) * 8;
        bf16x8 af[4], bfr[3];
#pragma unroll
        for (int mi = 0; mi < 4; mi++) af[mi] = *(const bf16x8*)&Al[(wm + mi * 16 + (lane & 15)) * LDA + kk];
#pragma unroll
        for (int ni = 0; ni < 3; ni++) bfr[ni] = *(const bf16x8*)&Bl[(wn + ni * 16 + (lane & 15)) * LDB + kk];
#pragma unroll
        for (int mi = 0; mi < 4; mi++)
#pragma unroll
            for (int ni = 0; ni < 3; ni++)
                acc[mi][ni] = __builtin_amdgcn_mfma_f32_16x16x32_bf16(af[mi], bfr[ni], acc[mi][ni], 0, 0, 0);
    }
#pragma unroll
    for (int mi = 0; mi < 4; mi++)
#pragma unroll
        for (int ni = 0; ni < 3; ni++)
#pragma unroll
            for (int r = 0; r < 4; r++) {
                int row = m0 + wm + mi * 16 + (lane >> 4) * 4 + r;
                int col = n0 + wn + ni * 16 + (lane & 15);
                float v = acc[mi][ni][r] + (col < NQKV ? bias[col] : 0.f);
                Cout[row * NQKVP + col] = f2bf(v);
            }
}

// ---------------- scatter q/k into [8][4096][96] (zero-padded d>=66) ----------------
__global__ void k_scatter_qk(const unsigned short* __restrict__ T,
                             unsigned short* __restrict__ qb, unsigned short* __restrict__ kb) {
    int idx = blockIdx.x * 256 + threadIdx.x;
    if (idx >= NH * N_TOK * HDP) return;
    int d = idx % HDP;
    int n = (idx / HDP) & (N_TOK - 1);
    int h = idx / (HDP * N_TOK);
    unsigned short zq = 0, zk = 0;
    if (d < HD) {
        zq = T[n * NQKVP + h * HD + d];
        zk = T[n * NQKVP + C + h * HD + d];
    }
    qb[idx] = zq; kb[idx] = zk;
}

// ---------------- v transpose into [8][80][4096] (zero-padded d>=66) ----------------
__global__ void k_transpose_v(const unsigned short* __restrict__ T, unsigned short* __restrict__ vt) {
    __shared__ unsigned short lt[64 * 88];
    int h = blockIdx.y, n0 = blockIdx.x * 64, tid = threadIdx.x;
#pragma unroll
    for (int i = 0; i < 20; i++) {
        int idx = i * 256 + tid;
        int ni = idx / 80, d = idx - ni * 80;
        unsigned short v = 0;
        if (d < HD) v = T[(n0 + ni) * NQKVP + 2 * C + h * HD + d];
        lt[ni * 88 + d] = v;
    }
    __syncthreads();
#pragma unroll
    for (int i = 0; i < 20; i++) {
        int idx = i * 256 + tid;
        int d = idx >> 6, ni = idx & 63;
        vt[(h * VDP + d) * N_TOK + n0 + ni] = lt[ni * 88 + d];
    }
}

// ---------------- flash attention ----------------
__launch_bounds__(256)
__global__ void k_attn(const unsigned short* __restrict__ qb,
                       const unsigned short* __restrict__ kb,
                       const unsigned short* __restrict__ vt,
                       unsigned short* __restrict__ ahi,
                       unsigned short* __restrict__ alo) {
    constexpr int LDK = 104, LDV = 136, LDP = 136;
    __shared__ unsigned short Kl[128 * LDK];   // K tile [128 keys][96], also reused for P after barrier
    __shared__ unsigned short Vl[VDP * LDV];   // V^T tile [80][128]
    int tid = threadIdx.x, lane = tid & 63, wid = tid >> 6;
    int head = blockIdx.y;
    int q0 = blockIdx.x * 64 + wid * 16;
    const float scale = 0.12309149097933274f;   // 66^-0.5
    const float LOG2E = 1.4426950408889634f;

    bf16x8 aq[3];
    {
        int row = q0 + (lane & 15);
        int kk = (lane >> 4) * 8;
        const unsigned short* qrow = qb + ((size_t)head * N_TOK + row) * HDP;
#pragma unroll
        for (int t = 0; t < 3; t++) aq[t] = *(const bf16x8*)&qrow[t * 32 + kk];
    }
    f32x4 o[5] = {};
    float m_r[4], l_r[4];
#pragma unroll
    for (int r = 0; r < 4; r++) { m_r[r] = -1e30f; l_r[r] = 0.f; }

    int kk = (lane >> 4) * 8;
    unsigned short* pw = &Kl[wid * 16 * LDP];

    for (int kt = 0; kt < N_TOK / 128; kt++) {
        int n0 = kt * 128;
        __syncthreads();   // everyone done with previous K/V/P
#pragma unroll
        for (int i = 0; i < 6; i++) {    // K: 128 rows x 12 chunks
            int c = i * 256 + tid;
            int row = c / 12, kc = (c - row * 12) * 8;
            *(bf16x8*)&Kl[row * LDK + kc] =
                *(const bf16x8*)&kb[((size_t)head * N_TOK + n0 + row) * HDP + kc];
        }
#pragma unroll
        for (int i = 0; i < 5; i++) {    // V^T: 80 rows x 16 chunks
            int c = i * 256 + tid;
            int row = c >> 4, nc = (c & 15) * 8;
            *(bf16x8*)&Vl[row * LDV + nc] =
                *(const bf16x8*)&vt[((size_t)head * VDP + row) * N_TOK + n0 + nc];
        }
        __syncthreads();

        // S = Q K^T
        f32x4 s[8];
#pragma unroll
        for (int nt = 0; nt < 8; nt++) s[nt] = (f32x4){0.f, 0.f, 0.f, 0.f};
#pragma unroll
        for (int t = 0; t < 3; t++) {
#pragma unroll
            for (int nt = 0; nt < 8; nt++) {
                bf16x8 bk = *(const bf16x8*)&Kl[(nt * 16 + (lane & 15)) * LDK + t * 32 + kk];
                s[nt] = __builtin_amdgcn_mfma_f32_16x16x32_bf16(aq[t], bk, s[nt], 0, 0, 0);
            }
        }
        // online softmax (rows owned: (lane>>4)*4 + r)
        float mnew[4], fct[4];
#pragma unroll
        for (int nt = 0; nt < 8; nt++)
#pragma unroll
            for (int r = 0; r < 4; r++) s[nt][r] *= scale;
#pragma unroll
        for (int r = 0; r < 4; r++) {
            float mx = fmaxf(fmaxf(fmaxf(s[0][r], s[1][r]), fmaxf(s[2][r], s[3][r])),
                             fmaxf(fmaxf(s[4][r], s[5][r]), fmaxf(s[6][r], s[7][r])));
#pragma unroll
            for (int off = 1; off < 16; off <<= 1) mx = fmaxf(mx, __shfl_xor(mx, off, 64));
            mnew[r] = fmaxf(m_r[r], mx);
            fct[r] = exp2f((m_r[r] - mnew[r]) * LOG2E);
            m_r[r] = mnew[r];
        }
#pragma unroll
        for (int nt = 0; nt < 8; nt++)
#pragma unroll
            for (int r = 0; r < 4; r++) s[nt][r] = exp2f((s[nt][r] - mnew[r]) * LOG2E);
#pragma unroll
        for (int r = 0; r < 4; r++) {
            float sm = 0.f;
#pragma unroll
            for (int nt = 0; nt < 8; nt++) sm += s[nt][r];
#pragma unroll
            for (int off = 1; off < 16; off <<= 1) sm += __shfl_xor(sm, off, 64);
            l_r[r] = l_r[r] * fct[r] + sm;
        }
#pragma unroll
        for (int v_ = 0; v_ < 5; v_++)
#pragma unroll
            for (int r = 0; r < 4; r++) o[v_][r] *= fct[r];

        __syncthreads();   // all waves done reading Kl -> safe to overwrite with P
#pragma unroll
        for (int nt = 0; nt < 8; nt++)
#pragma unroll
            for (int r = 0; r < 4; r++)
                pw[((lane >> 4) * 4 + r) * LDP + nt * 16 + (lane & 15)] = f2bf(s[nt][r]);
        asm volatile("s_waitcnt lgkmcnt(0)" ::: "memory");
        __builtin_amdgcn_sched_barrier(0);

        // O += P V
#pragma unroll
        for (int t2 = 0; t2 < 4; t2++) {
            bf16x8 pa = *(const bf16x8*)&pw[(lane & 15) * LDP + t2 * 32 + kk];
#pragma unroll
            for (int v_ = 0; v_ < 5; v_++) {
                bf16x8 bv = *(const bf16x8*)&Vl[(v_ * 16 + (lane & 15)) * LDV + t2 * 32 + kk];
                o[v_] = __builtin_amdgcn_mfma_f32_16x16x32_bf16(pa, bv, o[v_], 0, 0, 0);
            }
        }
    }
    // epilogue: out = O / l, store hi/lo bf16 split
#pragma unroll
    for (int v_ = 0; v_ < 5; v_++) {
        int col = v_ * 16 + (lane & 15);
        if (col < HD) {
#pragma unroll
            for (int r = 0; r < 4; r++) {
                int token = q0 + (lane >> 4) * 4 + r;
                float v = o[v_][r] / l_r[r];
                unsigned short hi = f2bf(v);
                float lo = v - bf2f(hi);
                size_t a = (size_t)token * KP + head * HD + col;
                ahi[a] = hi; alo[a] = f2bf(lo);
            }
        }
    }
}

// ---------------- proj GEMM (split-precision): [4096][544] @ [544][544]^T -> out[4096][528] fp32 ----------------
__launch_bounds__(256)
__global__ void k_gemm_proj(const unsigned short* __restrict__ Ahi_, const unsigned short* __restrict__ Alo_,
                            const unsigned short* __restrict__ Whi_, const unsigned short* __restrict__ Wlo_,
                            const float* __restrict__ bias, float* __restrict__ out) {
    constexpr int BM = 128, BN = 32, LDA = 40, LDB = 40;
    __shared__ unsigned short Ah[BM * LDA], Alw[BM * LDA], Bh[BN * LDB], Blw[BN * LDB];
    int tid = threadIdx.x, lane = tid & 63, wid = tid >> 6;
    int m0 = blockIdx.x * BM, n0 = blockIdx.y * BN;
    int wm = wid * 32;
    f32x4 acc[2][2] = {};
    for (int k0 = 0; k0 < KP; k0 += 32) {
        __syncthreads();
#pragma unroll
        for (int i = 0; i < 2; i++) {
            int c = i * 256 + tid;
            int row = c >> 2, kc = (c & 3) * 8;
            *(bf16x8*)&Ah[row * LDA + kc]  = *(const bf16x8*)&Ahi_[(size_t)(m0 + row) * KP + k0 + kc];
            *(bf16x8*)&Alw[row * LDA + kc] = *(const bf16x8*)&Alo_[(size_t)(m0 + row) * KP + k0 + kc];
        }
        if (tid < 128) {
            int row = tid >> 2, kc = (tid & 3) * 8;
            *(bf16x8*)&Bh[row * LDB + kc]  = *(const bf16x8*)&Whi_[(size_t)(n0 + row) * KP + k0 + kc];
            *(bf16x8*)&Blw[row * LDB + kc] = *(const bf16x8*)&Wlo_[(size_t)(n0 + row) * KP + k0 + kc];
        }
        __syncthreads();
        int kk = (lane >> 4) * 8;
        bf16x8 ah[2], al[2], bh[2], bl[2];
#pragma unroll
        for (int mi = 0; mi < 2; mi++) {
            ah[mi] = *(const bf16x8*)&Ah[(wm + mi * 16 + (lane & 15)) * LDA + kk];
            al[mi] = *(const bf16x8*)&Alw[(wm + mi * 16 + (lane & 15)) * LDA + kk];
        }
#pragma unroll
        for (int ni = 0; ni < 2; ni++) {
            bh[ni] = *(const bf16x8*)&Bh[(ni * 16 + (lane & 15)) * LDB + kk];
            bl[ni] = *(const bf16x8*)&Blw[(ni * 16 + (lane & 15)) * LDB + kk];
        }
#pragma unroll
        for (int mi = 0; mi < 2; mi++)
#pragma unroll
            for (int ni = 0; ni < 2; ni++) {
                acc[mi][ni] = __builtin_amdgcn_mfma_f32_16x16x32_bf16(ah[mi], bh[ni], acc[mi][ni], 0, 0, 0);
                acc[mi][ni] = __builtin_amdgcn_mfma_f32_16x16x32_bf16(ah[mi], bl[ni], acc[mi][ni], 0, 0, 0);
                acc[mi][ni] = __builtin_amdgcn_mfma_f32_16x16x32_bf16(al[mi], bh[ni], acc[mi][ni], 0, 0, 0);
            }
    }
#pragma unroll
    for (int mi = 0; mi < 2; mi++)
#pragma unroll
        for (int ni = 0; ni < 2; ni++)
#pragma unroll
            for (int r = 0; r < 4; r++) {
                int row = m0 + wm + mi * 16 + (lane >> 4) * 4 + r;
                int col = n0 + ni * 16 + (lane & 15);
                if (col < C) out[(size_t)row * C + col] = acc[mi][ni][r] + bias[col];
            }
}

extern "C" void kernel_launch(void* const* d_in, const int* in_sizes, int n_in,
                              void* d_out, int out_size, void* d_ws, size_t ws_size,
                              hipStream_t stream) {
    const float* x      = (const float*)d_in[0];
    const float* w_qkv  = (const float*)d_in[1];
    const float* b_qkv  = (const float*)d_in[2];
    const float* w_proj = (const float*)d_in[3];
    const float* b_proj = (const float*)d_in[4];
    float* out = (float*)d_out;
    char* ws = (char*)d_ws;

    // ws layout (bytes, all 256-aligned)
    const size_t o_xb     = 0;                         // 4096*544*2  = 4,456,448  (later aliased as ahi)
    const size_t o_wqkvb  = o_xb     + 4456448;        // 1632*544*2  = 1,775,616
    const size_t o_whi    = o_wqkvb  + 1775616;        // 544*544*2   =   591,872
    const size_t o_wlo    = o_whi    + 591872;
    const size_t o_qkvtmp = o_wlo    + 591872;         // 4096*1632*2 = 13,369,344 (later aliased as alo)
    const size_t o_qbf    = o_qkvtmp + 13369344;       // 8*4096*96*2 = 6,291,456
    const size_t o_kbf    = o_qbf    + 6291456;
    const size_t o_vt     = o_kbf    + 6291456;        // 8*80*4096*2 = 5,242,880
    const size_t need     = o_vt + 5242880;            // 38,610,944
    if (ws_size < need) return;  // cannot run without scratch; leave output poisoned

    unsigned short* xb     = (unsigned short*)(ws + o_xb);
    unsigned short* wqkvb  = (unsigned short*)(ws + o_wqkvb);
    unsigned short* whi    = (unsigned short*)(ws + o_whi);
    unsigned short* wlo    = (unsigned short*)(ws + o_wlo);
    unsigned short* qkvtmp = (unsigned short*)(ws + o_qkvtmp);
    unsigned short* qbf    = (unsigned short*)(ws + o_qbf);
    unsigned short* kbf    = (unsigned short*)(ws + o_kbf);
    unsigned short* vt     = (unsigned short*)(ws + o_vt);
    unsigned short* ahi    = xb;       // xb dead after k_gemm_qkv
    unsigned short* alo    = qkvtmp;   // qkvtmp dead after scatter/transpose

    k_prep_x    <<<(N_TOK * KP + 255) / 256, 256, 0, stream>>>(x, xb);
    k_prep_wqkv <<<(NQKVP * KP + 255) / 256, 256, 0, stream>>>(w_qkv, wqkvb);
    k_prep_wproj<<<(KP * KP + 255) / 256, 256, 0, stream>>>(w_proj, whi, wlo);
    k_gemm_qkv  <<<dim3(N_TOK / 128, NQKVP / 96), 256, 0, stream>>>(xb, wqkvb, b_qkv, qkvtmp);
    k_scatter_qk<<<(NH * N_TOK * HDP + 255) / 256, 256, 0, stream>>>(qkvtmp, qbf, kbf);
    k_transpose_v<<<dim3(N_TOK / 64, NH), 256, 0, stream>>>(qkvtmp, vt);
    k_zero_pads <<<(N_TOK * (KP - C) + 255) / 256, 256, 0, stream>>>(ahi, alo);
    k_attn      <<<dim3(N_TOK / 64, NH), 256, 0, stream>>>(qbf, kbf, vt, ahi, alo);
    k_gemm_proj <<<dim3(N_TOK / 128, KP / 32), 256, 0, stream>>>(ahi, alo, whi, wlo, b_proj, out);
}

// Round 2
// 218.615 us; speedup vs baseline: 1.0122x; 1.0122x over previous
//
#include <hip/hip_runtime.h>

typedef __attribute__((ext_vector_type(8))) short bf16x8;
typedef __attribute__((ext_vector_type(4))) float f32x4;

#define DEV __device__ __forceinline__

static constexpr int N_TOK = 4096;
static constexpr int C     = 528;
static constexpr int NH    = 8;
static constexpr int HD    = 66;
static constexpr int HDP   = 96;    // q/k head-dim padded (K-dim of QK^T MFMA)
static constexpr int VDP   = 80;    // v head-dim padded (N-dim of PV MFMA)
static constexpr int KP    = 544;   // GEMM K padded 528->544 (17*32)
static constexpr int NQKV  = 1584;
static constexpr int NQKVP = 1632;  // 17*96

DEV unsigned short f2bf(float f) {
    unsigned int u = __float_as_uint(f);
    u = (u + 0x7fffu + ((u >> 16) & 1u)) >> 16;
    return (unsigned short)u;
}
DEV float bf2f(unsigned short h) { return __uint_as_float(((unsigned int)h) << 16); }
DEV unsigned cvtpk2(float a, float b) {
    unsigned r;
    asm("v_cvt_pk_bf16_f32 %0, %1, %2" : "=v"(r) : "v"(a), "v"(b));
    return r;
}

// ---------------- prep ----------------
__global__ void k_prep_x(const float* __restrict__ x, unsigned short* __restrict__ xb) {
    int idx = blockIdx.x * 256 + threadIdx.x;
    if (idx >= N_TOK * KP) return;
    int n = idx / KP, k = idx - n * KP;
    xb[idx] = (k < C) ? f2bf(x[n * C + k]) : (unsigned short)0;
}
__global__ void k_prep_wqkv(const float* __restrict__ w, unsigned short* __restrict__ wb) {
    int idx = blockIdx.x * 256 + threadIdx.x;
    if (idx >= NQKVP * KP) return;
    int n = idx / KP, k = idx - n * KP;
    wb[idx] = (n < NQKV && k < C) ? f2bf(w[n * C + k]) : (unsigned short)0;
}
__global__ void k_prep_wproj(const float* __restrict__ w, unsigned short* __restrict__ whi,
                             unsigned short* __restrict__ wlo) {
    int idx = blockIdx.x * 256 + threadIdx.x;
    if (idx >= KP * KP) return;
    int n = idx / KP, k = idx - n * KP;
    unsigned short hi = 0, lo = 0;
    if (n < C && k < C) {
        float v = w[n * C + k];
        hi = f2bf(v);
        lo = f2bf(v - bf2f(hi));
    }
    whi[idx] = hi; wlo[idx] = lo;
}
__global__ void k_zero_pads(unsigned short* __restrict__ ahi, unsigned short* __restrict__ alo) {
    int idx = blockIdx.x * 256 + threadIdx.x;
    if (idx >= N_TOK * (KP - C)) return;
    int n = idx >> 4, c = C + (idx & 15);
    ahi[n * KP + c] = 0; alo[n * KP + c] = 0;
}

// ---------------- QKV GEMM: xb[4096][544] @ wqkvb[1632][544]^T -> qkv_tmp[4096][1632] bf16 ----------------
__launch_bounds__(256)
__global__ void k_gemm_qkv(const unsigned short* __restrict__ A,
                           const unsigned short* __restrict__ B,
                           const float* __restrict__ bias,
                           unsigned short* __restrict__ Cout) {
    constexpr int BM = 128, BN = 96, LDA = 40, LDB = 40;
    __shared__ unsigned short Al[BM * LDA];
    __shared__ unsigned short Bl[BN * LDB];
    int tid = threadIdx.x, lane = tid & 63, wid = tid >> 6;
    int m0 = blockIdx.x * BM, n0 = blockIdx.y * BN;
    int wm = (wid >> 1) * 64;
    int wn = (wid & 1) * 48;
    f32x4 acc[4][3] = {};
    for (int k0 = 0; k0 < KP; k0 += 32) {
        __syncthreads();
#pragma unroll
        for (int i = 0; i < 2; i++) {
            int c = i * 256 + tid;
            int row = c >> 2, kc = (c & 3) * 8;
            *(bf16x8*)&Al[row * LDA + kc] = *(const bf16x8*)&A[(m0 + row) * KP + k0 + kc];
        }
        {
            int c = tid, row = c >> 2, kc = (c & 3) * 8;
            *(bf16x8*)&Bl[row * LDB + kc] = *(const bf16x8*)&B[(n0 + row) * KP + k0 + kc];
            c = 256 + tid;
            if (c < 384) {
                row = c >> 2; kc = (c & 3) * 8;
                *(bf16x8*)&Bl[row * LDB + kc] = *(const bf16x8*)&B[(n0 + row) * KP + k0 + kc];
            }
        }
        __syncthreads();
        int kk = (lane >> 4) * 8;
        bf16x8 af[4], bfr[3];
#pragma unroll
        for (int mi = 0; mi < 4; mi++) af[mi] = *(const bf16x8*)&Al[(wm + mi * 16 + (lane & 15)) * LDA + kk];
#pragma unroll
        for (int ni = 0; ni < 3; ni++) bfr[ni] = *(const bf16x8*)&Bl[(wn + ni * 16 + (lane & 15)) * LDB + kk];
#pragma unroll
        for (int mi = 0; mi < 4; mi++)
#pragma unroll
            for (int ni = 0; ni < 3; ni++)
                acc[mi][ni] = __builtin_amdgcn_mfma_f32_16x16x32_bf16(af[mi], bfr[ni], acc[mi][ni], 0, 0, 0);
    }
#pragma unroll
    for (int mi = 0; mi < 4; mi++)
#pragma unroll
        for (int ni = 0; ni < 3; ni++)
#pragma unroll
            for (int r = 0; r < 4; r++) {
                int row = m0 + wm + mi * 16 + (lane >> 4) * 4 + r;
                int col = n0 + wn + ni * 16 + (lane & 15);
                float v = acc[mi][ni][r] + (col < NQKV ? bias[col] : 0.f);
                Cout[row * NQKVP + col] = f2bf(v);
            }
}

// ---------------- scatter q/k into [8][4096][96] (zero-padded d>=66) ----------------
__global__ void k_scatter_qk(const unsigned short* __restrict__ T,
                             unsigned short* __restrict__ qb, unsigned short* __restrict__ kb) {
    int idx = blockIdx.x * 256 + threadIdx.x;
    if (idx >= NH * N_TOK * HDP) return;
    int d = idx % HDP;
    int n = (idx / HDP) & (N_TOK - 1);
    int h = idx / (HDP * N_TOK);
    unsigned short zq = 0, zk = 0;
    if (d < HD) {
        zq = T[n * NQKVP + h * HD + d];
        zk = T[n * NQKVP + C + h * HD + d];
    }
    qb[idx] = zq; kb[idx] = zk;
}

// ---------------- v transpose into [8][80][4096] (zero-padded d>=66) ----------------
__global__ void k_transpose_v(const unsigned short* __restrict__ T, unsigned short* __restrict__ vt) {
    __shared__ unsigned short lt[64 * 88];
    int h = blockIdx.y, n0 = blockIdx.x * 64, tid = threadIdx.x;
#pragma unroll
    for (int i = 0; i < 20; i++) {
        int idx = i * 256 + tid;
        int ni = idx / 80, d = idx - ni * 80;
        unsigned short v = 0;
        if (d < HD) v = T[(n0 + ni) * NQKVP + 2 * C + h * HD + d];
        lt[ni * 88 + d] = v;
    }
    __syncthreads();
#pragma unroll
    for (int i = 0; i < 20; i++) {
        int idx = i * 256 + tid;
        int d = idx >> 6, ni = idx & 63;
        vt[(h * VDP + d) * N_TOK + n0 + ni] = lt[ni * 88 + d];
    }
}

// ---------------- flash attention: 8 waves, 64 q-rows/block, wave-pair split over key halves ----------------
__launch_bounds__(512, 4)
__global__ void k_attn(const unsigned short* __restrict__ qb,
                       const unsigned short* __restrict__ kb,
                       const unsigned short* __restrict__ vt,
                       unsigned short* __restrict__ ahi,
                       unsigned short* __restrict__ alo) {
    constexpr int LDK = 104, LDV = 136, LDP = 136;
    __shared__ __align__(16) unsigned short Kl[128 * LDK];   // K tile [128 keys][96]; reused fp32 for end-combine
    __shared__ __align__(16) unsigned short Vl[VDP * LDV];   // V^T tile [80][128]
    __shared__ __align__(16) unsigned short Pl[64 * LDP];    // P tile [64 qrows][128 keys]
    int tid = threadIdx.x, lane = tid & 63, wid = tid >> 6;
    int wq = wid & 3;          // q-row-tile (16 rows) within block
    int gsel = wid >> 2;       // key half within each staged tile
    int head = blockIdx.y;
    int q0 = blockIdx.x * 64 + wq * 16;
    const float SC2 = 0.12309149097933274f * 1.4426950408889634f;  // 66^-0.5 * log2(e)

    bf16x8 aq[3];
    {
        int row = q0 + (lane & 15);
        int kx = (lane >> 4) * 8;
        const unsigned short* qrow = qb + ((size_t)head * N_TOK + row) * HDP;
#pragma unroll
        for (int t = 0; t < 3; t++) aq[t] = *(const bf16x8*)&qrow[t * 32 + kx];
    }
    f32x4 o[5] = {};
    float m_r[4], l_r[4];
#pragma unroll
    for (int r = 0; r < 4; r++) { m_r[r] = -1e30f; l_r[r] = 0.f; }

    int kk = (lane >> 4) * 8;
    int cc = lane & 15;
    unsigned short* pw = &Pl[wq * 16 * LDP + gsel * 64];

    for (int kt = 0; kt < N_TOK / 128; kt++) {
        int n0 = kt * 128;
        __syncthreads();
#pragma unroll
        for (int i = 0; i < 3; i++) {     // K: 128 rows x 12 b128 chunks = 1536
            int c = i * 512 + tid;
            int row = c / 12, kc = (c - row * 12) * 8;
            *(bf16x8*)&Kl[row * LDK + kc] =
                *(const bf16x8*)&kb[((size_t)head * N_TOK + n0 + row) * HDP + kc];
        }
#pragma unroll
        for (int i = 0; i < 3; i++) {     // V^T: 80 rows x 16 chunks = 1280
            int c = i * 512 + tid;
            if (c < 1280) {
                int row = c >> 4, nc = (c & 15) * 8;
                *(bf16x8*)&Vl[row * LDV + nc] =
                    *(const bf16x8*)&vt[((size_t)head * VDP + row) * N_TOK + n0 + nc];
            }
        }
        __syncthreads();

        // S = Q K^T over this wave's 64-key half
        f32x4 s[4];
#pragma unroll
        for (int nt = 0; nt < 4; nt++) s[nt] = (f32x4){0.f, 0.f, 0.f, 0.f};
#pragma unroll
        for (int t = 0; t < 3; t++) {
#pragma unroll
            for (int nt = 0; nt < 4; nt++) {
                bf16x8 bk = *(const bf16x8*)&Kl[(gsel * 64 + nt * 16 + cc) * LDK + t * 32 + kk];
                s[nt] = __builtin_amdgcn_mfma_f32_16x16x32_bf16(aq[t], bk, s[nt], 0, 0, 0);
            }
        }
        // online softmax in log2 domain
        float mnew[4], fct[4];
#pragma unroll
        for (int nt = 0; nt < 4; nt++)
#pragma unroll
            for (int r = 0; r < 4; r++) s[nt][r] *= SC2;
#pragma unroll
        for (int r = 0; r < 4; r++) {
            float mx = fmaxf(fmaxf(s[0][r], s[1][r]), fmaxf(s[2][r], s[3][r]));
#pragma unroll
            for (int off = 1; off < 16; off <<= 1) mx = fmaxf(mx, __shfl_xor(mx, off, 64));
            mnew[r] = fmaxf(m_r[r], mx);
            fct[r] = __builtin_amdgcn_exp2f(m_r[r] - mnew[r]);
            m_r[r] = mnew[r];
        }
#pragma unroll
        for (int nt = 0; nt < 4; nt++)
#pragma unroll
            for (int r = 0; r < 4; r++) s[nt][r] = __builtin_amdgcn_exp2f(s[nt][r] - mnew[r]);
#pragma unroll
        for (int r = 0; r < 4; r++) {
            float sm = (s[0][r] + s[1][r]) + (s[2][r] + s[3][r]);
#pragma unroll
            for (int off = 1; off < 16; off <<= 1) sm += __shfl_xor(sm, off, 64);
            l_r[r] = l_r[r] * fct[r] + sm;
        }
#pragma unroll
        for (int v_ = 0; v_ < 5; v_++)
#pragma unroll
            for (int r = 0; r < 4; r++) o[v_][r] *= fct[r];

        // P -> LDS bf16 (wave-private region; no barrier needed)
#pragma unroll
        for (int nt = 0; nt < 4; nt++) {
            unsigned u01 = cvtpk2(s[nt][0], s[nt][1]);
            unsigned u23 = cvtpk2(s[nt][2], s[nt][3]);
            unsigned short* b = pw + ((lane >> 4) * 4) * LDP + nt * 16 + cc;
            b[0]       = (unsigned short)u01;
            b[LDP]     = (unsigned short)(u01 >> 16);
            b[2 * LDP] = (unsigned short)u23;
            b[3 * LDP] = (unsigned short)(u23 >> 16);
        }
        asm volatile("s_waitcnt lgkmcnt(0)" ::: "memory");
        __builtin_amdgcn_sched_barrier(0);

        // O += P V over this wave's key half
#pragma unroll
        for (int t2 = 0; t2 < 2; t2++) {
            bf16x8 pa = *(const bf16x8*)&Pl[(wq * 16 + cc) * LDP + gsel * 64 + t2 * 32 + kk];
#pragma unroll
            for (int v_ = 0; v_ < 5; v_++) {
                bf16x8 bv = *(const bf16x8*)&Vl[(v_ * 16 + cc) * LDV + gsel * 64 + t2 * 32 + kk];
                o[v_] = __builtin_amdgcn_mfma_f32_16x16x32_bf16(pa, bv, o[v_], 0, 0, 0);
            }
        }
    }

    // ---- combine the two key-half partials (wave w with wave w+4) via LDS ----
    __syncthreads();
    float* xch = (float*)Kl;                 // [64 rows][84 floats]
    int rbase = wq * 16 + (lane >> 4) * 4;
    if (gsel == 1) {
#pragma unroll
        for (int r = 0; r < 4; r++) {
            xch[(rbase + r) * 84 + 80] = m_r[r];
            xch[(rbase + r) * 84 + 81] = l_r[r];
        }
#pragma unroll
        for (int v_ = 0; v_ < 5; v_++)
#pragma unroll
            for (int r = 0; r < 4; r++)
                xch[(rbase + r) * 84 + v_ * 16 + cc] = o[v_][r];
    }
    __syncthreads();
    if (gsel == 0) {
        float fa[4], fb[4], li[4];
#pragma unroll
        for (int r = 0; r < 4; r++) {
            float mb = xch[(rbase + r) * 84 + 80];
            float lb = xch[(rbase + r) * 84 + 81];
            float m = fmaxf(m_r[r], mb);
            fa[r] = __builtin_amdgcn_exp2f(m_r[r] - m);
            fb[r] = __builtin_amdgcn_exp2f(mb - m);
            li[r] = 1.f / (l_r[r] * fa[r] + lb * fb[r]);
        }
#pragma unroll
        for (int v_ = 0; v_ < 5; v_++) {
            int col = v_ * 16 + cc;
            if (col < HD) {
#pragma unroll
                for (int r = 0; r < 4; r++) {
                    int token = q0 + (lane >> 4) * 4 + r;
                    float val = (o[v_][r] * fa[r] + xch[(rbase + r) * 84 + col] * fb[r]) * li[r];
                    unsigned short hi = f2bf(val);
                    float lo = val - bf2f(hi);
                    size_t a = (size_t)token * KP + head * HD + col;
                    ahi[a] = hi; alo[a] = f2bf(lo);
                }
            }
        }
    }
}

// ---------------- proj GEMM (split-precision): [4096][544] @ [544][544]^T -> out[4096][528] fp32 ----------------
__launch_bounds__(256)
__global__ void k_gemm_proj(const unsigned short* __restrict__ Ahi_, const unsigned short* __restrict__ Alo_,
                            const unsigned short* __restrict__ Whi_, const unsigned short* __restrict__ Wlo_,
                            const float* __restrict__ bias, float* __restrict__ out) {
    constexpr int BM = 128, BN = 32, LDA = 40, LDB = 40;
    __shared__ unsigned short Ah[BM * LDA], Alw[BM * LDA], Bh[BN * LDB], Blw[BN * LDB];
    int tid = threadIdx.x, lane = tid & 63, wid = tid >> 6;
    int m0 = blockIdx.x * BM, n0 = blockIdx.y * BN;
    int wm = wid * 32;
    f32x4 acc[2][2] = {};
    for (int k0 = 0; k0 < KP; k0 += 32) {
        __syncthreads();
#pragma unroll
        for (int i = 0; i < 2; i++) {
            int c = i * 256 + tid;
            int row = c >> 2, kc = (c & 3) * 8;
            *(bf16x8*)&Ah[row * LDA + kc]  = *(const bf16x8*)&Ahi_[(size_t)(m0 + row) * KP + k0 + kc];
            *(bf16x8*)&Alw[row * LDA + kc] = *(const bf16x8*)&Alo_[(size_t)(m0 + row) * KP + k0 + kc];
        }
        if (tid < 128) {
            int row = tid >> 2, kc = (tid & 3) * 8;
            *(bf16x8*)&Bh[row * LDB + kc]  = *(const bf16x8*)&Whi_[(size_t)(n0 + row) * KP + k0 + kc];
            *(bf16x8*)&Blw[row * LDB + kc] = *(const bf16x8*)&Wlo_[(size_t)(n0 + row) * KP + k0 + kc];
        }
        __syncthreads();
        int kk = (lane >> 4) * 8;
        bf16x8 ah[2], al[2], bh[2], bl[2];
#pragma unroll
        for (int mi = 0; mi < 2; mi++) {
            ah[mi] = *(const bf16x8*)&Ah[(wm + mi * 16 + (lane & 15)) * LDA + kk];
            al[mi] = *(const bf16x8*)&Alw[(wm + mi * 16 + (lane & 15)) * LDA + kk];
        }
#pragma unroll
        for (int ni = 0; ni < 2; ni++) {
            bh[ni] = *(const bf16x8*)&Bh[(ni * 16 + (lane & 15)) * LDB + kk];
            bl[ni] = *(const bf16x8*)&Blw[(ni * 16 + (lane & 15)) * LDB + kk];
        }
#pragma unroll
        for (int mi = 0; mi < 2; mi++)
#pragma unroll
            for (int ni = 0; ni < 2; ni++) {
                acc[mi][ni] = __builtin_amdgcn_mfma_f32_16x16x32_bf16(ah[mi], bh[ni], acc[mi][ni], 0, 0, 0);
                acc[mi][ni] = __builtin_amdgcn_mfma_f32_16x16x32_bf16(ah[mi], bl[ni], acc[mi][ni], 0, 0, 0);
                acc[mi][ni] = __builtin_amdgcn_mfma_f32_16x16x32_bf16(al[mi], bh[ni], acc[mi][ni], 0, 0, 0);
            }
    }
#pragma unroll
    for (int mi = 0; mi < 2; mi++)
#pragma unroll
        for (int ni = 0; ni < 2; ni++)
#pragma unroll
            for (int r = 0; r < 4; r++) {
                int row = m0 + wm + mi * 16 + (lane >> 4) * 4 + r;
                int col = n0 + ni * 16 + (lane & 15);
                if (col < C) out[(size_t)row * C + col] = acc[mi][ni][r] + bias[col];
            }
}

extern "C" void kernel_launch(void* const* d_in, const int* in_sizes, int n_in,
                              void* d_out, int out_size, void* d_ws, size_t ws_size,
                              hipStream_t stream) {
    const float* x      = (const float*)d_in[0];
    const float* w_qkv  = (const float*)d_in[1];
    const float* b_qkv  = (const float*)d_in[2];
    const float* w_proj = (const float*)d_in[3];
    const float* b_proj = (const float*)d_in[4];
    float* out = (float*)d_out;
    char* ws = (char*)d_ws;

    const size_t o_xb     = 0;
    const size_t o_wqkvb  = o_xb     + 4456448;
    const size_t o_whi    = o_wqkvb  + 1775616;
    const size_t o_wlo    = o_whi    + 591872;
    const size_t o_qkvtmp = o_wlo    + 591872;
    const size_t o_qbf    = o_qkvtmp + 13369344;
    const size_t o_kbf    = o_qbf    + 6291456;
    const size_t o_vt     = o_kbf    + 6291456;
    const size_t need     = o_vt + 5242880;
    if (ws_size < need) return;

    unsigned short* xb     = (unsigned short*)(ws + o_xb);
    unsigned short* wqkvb  = (unsigned short*)(ws + o_wqkvb);
    unsigned short* whi    = (unsigned short*)(ws + o_whi);
    unsigned short* wlo    = (unsigned short*)(ws + o_wlo);
    unsigned short* qkvtmp = (unsigned short*)(ws + o_qkvtmp);
    unsigned short* qbf    = (unsigned short*)(ws + o_qbf);
    unsigned short* kbf    = (unsigned short*)(ws + o_kbf);
    unsigned short* vt     = (unsigned short*)(ws + o_vt);
    unsigned short* ahi    = xb;
    unsigned short* alo    = qkvtmp;

    k_prep_x    <<<(N_TOK * KP + 255) / 256, 256, 0, stream>>>(x, xb);
    k_prep_wqkv <<<(NQKVP * KP + 255) / 256, 256, 0, stream>>>(w_qkv, wqkvb);
    k_prep_wproj<<<(KP * KP + 255) / 256, 256, 0, stream>>>(w_proj, whi, wlo);
    k_gemm_qkv  <<<dim3(N_TOK / 128, NQKVP / 96), 256, 0, stream>>>(xb, wqkvb, b_qkv, qkvtmp);
    k_scatter_qk<<<(NH * N_TOK * HDP + 255) / 256, 256, 0, stream>>>(qkvtmp, qbf, kbf);
    k_transpose_v<<<dim3(N_TOK / 64, NH), 256, 0, stream>>>(qkvtmp, vt);
    k_zero_pads <<<(N_TOK * (KP - C) + 255) / 256, 256, 0, stream>>>(ahi, alo);
    k_attn      <<<dim3(N_TOK / 64, NH), 512, 0, stream>>>(qbf, kbf, vt, ahi, alo);
    k_gemm_proj <<<dim3(N_TOK / 128, KP / 32), 256, 0, stream>>>(ahi, alo, whi, wlo, b_proj, out);
}

// Round 3
// 147.266 us; speedup vs baseline: 1.5026x; 1.4845x over previous
//
#include <hip/hip_runtime.h>

typedef __attribute__((ext_vector_type(8))) short bf16x8;
typedef __attribute__((ext_vector_type(4))) float f32x4;
typedef __attribute__((ext_vector_type(16))) float f32x16;

#define DEV __device__ __forceinline__

static constexpr int N_TOK = 4096;
static constexpr int C     = 528;
static constexpr int NH    = 8;
static constexpr int HD    = 66;
static constexpr int HDP   = 96;    // q/k head-dim padded
static constexpr int VD96  = 96;    // v head-dim padded to 96 (3 x 32 d-blocks)
static constexpr int KP    = 544;   // GEMM K padded 528->544 (17*32)
static constexpr int NQKV  = 1584;
static constexpr int NQKVP = 1632;  // 17*96

DEV unsigned short f2bf(float f) {
    unsigned int u = __float_as_uint(f);
    u = (u + 0x7fffu + ((u >> 16) & 1u)) >> 16;
    return (unsigned short)u;
}
DEV float bf2f(unsigned short h) { return __uint_as_float(((unsigned int)h) << 16); }
DEV unsigned cvtpk2(float a, float b) {
    unsigned r;
    asm("v_cvt_pk_bf16_f32 %0, %1, %2" : "=v"(r) : "v"(a), "v"(b));
    return r;
}
// dst'[32+i]=src[i]; src'[i]=dst[32+i]  (swap dst upper lanes with src lower lanes)
DEV void plswap(unsigned &a, unsigned &b) {
    asm volatile("v_permlane32_swap_b32 %0, %1" : "+v"(a), "+v"(b));
}

// ---------------- prep ----------------
__global__ void k_prep_x(const float* __restrict__ x, unsigned short* __restrict__ xb) {
    int idx = blockIdx.x * 256 + threadIdx.x;
    if (idx >= N_TOK * KP) return;
    int n = idx / KP, k = idx - n * KP;
    xb[idx] = (k < C) ? f2bf(x[n * C + k]) : (unsigned short)0;
}
__global__ void k_prep_wqkv(const float* __restrict__ w, unsigned short* __restrict__ wb) {
    int idx = blockIdx.x * 256 + threadIdx.x;
    if (idx >= NQKVP * KP) return;
    int n = idx / KP, k = idx - n * KP;
    wb[idx] = (n < NQKV && k < C) ? f2bf(w[n * C + k]) : (unsigned short)0;
}
__global__ void k_prep_wproj(const float* __restrict__ w, unsigned short* __restrict__ whi,
                             unsigned short* __restrict__ wlo) {
    int idx = blockIdx.x * 256 + threadIdx.x;
    if (idx >= KP * KP) return;
    int n = idx / KP, k = idx - n * KP;
    unsigned short hi = 0, lo = 0;
    if (n < C && k < C) {
        float v = w[n * C + k];
        hi = f2bf(v);
        lo = f2bf(v - bf2f(hi));
    }
    whi[idx] = hi; wlo[idx] = lo;
}
__global__ void k_zero_pads(unsigned short* __restrict__ ahi, unsigned short* __restrict__ alo) {
    int idx = blockIdx.x * 256 + threadIdx.x;
    if (idx >= N_TOK * (KP - C)) return;
    int n = idx >> 4, c = C + (idx & 15);
    ahi[n * KP + c] = 0; alo[n * KP + c] = 0;
}

// ---------------- QKV GEMM ----------------
__launch_bounds__(256)
__global__ void k_gemm_qkv(const unsigned short* __restrict__ A,
                           const unsigned short* __restrict__ B,
                           const float* __restrict__ bias,
                           unsigned short* __restrict__ Cout) {
    constexpr int BM = 128, BN = 96, LDA = 40, LDB = 40;
    __shared__ unsigned short Al[BM * LDA];
    __shared__ unsigned short Bl[BN * LDB];
    int tid = threadIdx.x, lane = tid & 63, wid = tid >> 6;
    int m0 = blockIdx.x * BM, n0 = blockIdx.y * BN;
    int wm = (wid >> 1) * 64;
    int wn = (wid & 1) * 48;
    f32x4 acc[4][3] = {};
    for (int k0 = 0; k0 < KP; k0 += 32) {
        __syncthreads();
#pragma unroll
        for (int i = 0; i < 2; i++) {
            int c = i * 256 + tid;
            int row = c >> 2, kc = (c & 3) * 8;
            *(bf16x8*)&Al[row * LDA + kc] = *(const bf16x8*)&A[(m0 + row) * KP + k0 + kc];
        }
        {
            int c = tid, row = c >> 2, kc = (c & 3) * 8;
            *(bf16x8*)&Bl[row * LDB + kc] = *(const bf16x8*)&B[(n0 + row) * KP + k0 + kc];
            c = 256 + tid;
            if (c < 384) {
                row = c >> 2; kc = (c & 3) * 8;
                *(bf16x8*)&Bl[row * LDB + kc] = *(const bf16x8*)&B[(n0 + row) * KP + k0 + kc];
            }
        }
        __syncthreads();
        int kk = (lane >> 4) * 8;
        bf16x8 af[4], bfr[3];
#pragma unroll
        for (int mi = 0; mi < 4; mi++) af[mi] = *(const bf16x8*)&Al[(wm + mi * 16 + (lane & 15)) * LDA + kk];
#pragma unroll
        for (int ni = 0; ni < 3; ni++) bfr[ni] = *(const bf16x8*)&Bl[(wn + ni * 16 + (lane & 15)) * LDB + kk];
#pragma unroll
        for (int mi = 0; mi < 4; mi++)
#pragma unroll
            for (int ni = 0; ni < 3; ni++)
                acc[mi][ni] = __builtin_amdgcn_mfma_f32_16x16x32_bf16(af[mi], bfr[ni], acc[mi][ni], 0, 0, 0);
    }
#pragma unroll
    for (int mi = 0; mi < 4; mi++)
#pragma unroll
        for (int ni = 0; ni < 3; ni++)
#pragma unroll
            for (int r = 0; r < 4; r++) {
                int row = m0 + wm + mi * 16 + (lane >> 4) * 4 + r;
                int col = n0 + wn + ni * 16 + (lane & 15);
                float v = acc[mi][ni][r] + (col < NQKV ? bias[col] : 0.f);
                Cout[row * NQKVP + col] = f2bf(v);
            }
}

// ---------------- scatter q/k into [8][4096][96] ----------------
__global__ void k_scatter_qk(const unsigned short* __restrict__ T,
                             unsigned short* __restrict__ qb, unsigned short* __restrict__ kb) {
    int idx = blockIdx.x * 256 + threadIdx.x;
    if (idx >= NH * N_TOK * HDP) return;
    int d = idx % HDP;
    int n = (idx / HDP) & (N_TOK - 1);
    int h = idx / (HDP * N_TOK);
    unsigned short zq = 0, zk = 0;
    if (d < HD) {
        zq = T[n * NQKVP + h * HD + d];
        zk = T[n * NQKVP + C + h * HD + d];
    }
    qb[idx] = zq; kb[idx] = zk;
}

// ---------------- v transpose into [8][96][4096] (zero-padded d>=66) ----------------
__global__ void k_transpose_v(const unsigned short* __restrict__ T, unsigned short* __restrict__ vt) {
    __shared__ unsigned short lt[64 * 104];
    int h = blockIdx.y, n0 = blockIdx.x * 64, tid = threadIdx.x;
#pragma unroll
    for (int i = 0; i < 24; i++) {
        int idx = i * 256 + tid;
        int ni = idx / 96, d = idx - ni * 96;
        unsigned short v = 0;
        if (d < HD) v = T[(n0 + ni) * NQKVP + 2 * C + h * HD + d];
        lt[ni * 104 + d] = v;
    }
    __syncthreads();
#pragma unroll
    for (int i = 0; i < 24; i++) {
        int idx = i * 256 + tid;
        int d = idx >> 6, ni = idx & 63;
        vt[((size_t)h * VD96 + d) * N_TOK + n0 + ni] = lt[ni * 104 + d];
    }
}

// ---------------- flash attention: swapped QK^T, 32x32 MFMA, in-register P ----------------
// 8 waves = 4 q-groups x 2 key-halves; QBLK=128; KV tile 128 keys, double-buffered.
__launch_bounds__(512, 2)
__global__ void k_attn(const unsigned short* __restrict__ qb,
                       const unsigned short* __restrict__ kb,
                       const unsigned short* __restrict__ vt,
                       unsigned short* __restrict__ ahi,
                       unsigned short* __restrict__ alo) {
    __shared__ __align__(16) unsigned short Kl[2][128 * 128];  // [key][96->16 swizzled slots]
    __shared__ __align__(16) unsigned short Vl[2][96 * 128];   // [d][128 keys swizzled]
    int tid = threadIdx.x, lane = tid & 63, wid = tid >> 6;
    int wq = wid & 3, kh = wid >> 2;
    int hi = lane >> 5, lq = lane & 31;
    int bid = blockIdx.x;
    int head = bid & 7;                 // head == XCD -> K/V L2-resident per XCD
    int q0 = (bid >> 3) * 128;
    const float SC2 = 0.12309149097933274f * 1.4426950408889634f;  // 66^-0.5 * log2(e)

    // Q fragments (B-operand): col=q=lane&31, k=(lane>>5)*8+j
    bf16x8 aq[6];
    {
        const unsigned short* qrow = qb + ((size_t)head * N_TOK + q0 + wq * 32 + lq) * HDP + hi * 8;
#pragma unroll
        for (int t = 0; t < 6; t++) aq[t] = *(const bf16x8*)&qrow[t * 16];
    }
    f32x16 o0 = {}, o1 = {}, o2 = {};
    float m_r = -3e38f, l_r = 0.f;

    const unsigned short* kg = kb + (size_t)head * N_TOK * HDP;
    const unsigned short* vg = vt + (size_t)head * VD96 * N_TOK;

    // prologue: stage tile 0
#pragma unroll
    for (int i = 0; i < 3; i++) {
        int c = i * 512 + tid;
        int row = c / 12, ch = c - row * 12;
        *(bf16x8*)&Kl[0][row * 128 + ((ch ^ (row & 15)) << 3)] =
            *(const bf16x8*)&kg[(size_t)row * HDP + ch * 8];
    }
#pragma unroll
    for (int i = 0; i < 3; i++) {
        int c = i * 512 + tid;
        int row = c >> 4, ch = c & 15;
        *(bf16x8*)&Vl[0][row * 128 + ((ch ^ (row & 15)) << 3)] =
            *(const bf16x8*)&vg[(size_t)row * N_TOK + ch * 8];
    }
    __syncthreads();

    for (int kt = 0; kt < 32; kt++) {
        int cur = kt & 1;
        // T14: issue next tile's global loads now; consume at tile bottom
        bf16x8 gk[3], gv[3];
        if (kt < 31) {
            int n1 = (kt + 1) * 128;
#pragma unroll
            for (int i = 0; i < 3; i++) {
                int c = i * 512 + tid;
                int row = c / 12, ch = c - row * 12;
                gk[i] = *(const bf16x8*)&kg[(size_t)(n1 + row) * HDP + ch * 8];
            }
#pragma unroll
            for (int i = 0; i < 3; i++) {
                int c = i * 512 + tid;
                int row = c >> 4, ch = c & 15;
                gv[i] = *(const bf16x8*)&vg[(size_t)row * N_TOK + n1 + ch * 8];
            }
        }

        // S = K Q^T : S[key][q], key = kh*64 + kb*32 + (r&3)+8*(r>>2)+4*hi, q = lq
        f32x16 s0 = {}, s1 = {};
        {
            int r0 = kh * 64 + lq, r1 = r0 + 32;
#pragma unroll
            for (int t = 0; t < 6; t++) {
                bf16x8 ka0 = *(const bf16x8*)&Kl[cur][r0 * 128 + (((2 * t + hi) ^ (r0 & 15)) << 3)];
                bf16x8 ka1 = *(const bf16x8*)&Kl[cur][r1 * 128 + (((2 * t + hi) ^ (r1 & 15)) << 3)];
                s0 = __builtin_amdgcn_mfma_f32_32x32x16_bf16(ka0, aq[t], s0, 0, 0, 0);
                s1 = __builtin_amdgcn_mfma_f32_32x32x16_bf16(ka1, aq[t], s1, 0, 0, 0);
            }
        }

        // online softmax: all reductions in-lane + one xor-32 swap
        float mx = s0[0];
#pragma unroll
        for (int r = 1; r < 16; r++) mx = fmaxf(mx, s0[r]);
#pragma unroll
        for (int r = 0; r < 16; r++) mx = fmaxf(mx, s1[r]);
        mx = fmaxf(mx, __shfl_xor(mx, 32, 64));
        float mnew = fmaxf(m_r, mx);
        float fct = __builtin_amdgcn_exp2f((m_r - mnew) * SC2);
        m_r = mnew;
        float nb = mnew * SC2;
        float lsum = 0.f;
#pragma unroll
        for (int r = 0; r < 16; r++) { s0[r] = __builtin_amdgcn_exp2f(__builtin_fmaf(s0[r], SC2, -nb)); lsum += s0[r]; }
#pragma unroll
        for (int r = 0; r < 16; r++) { s1[r] = __builtin_amdgcn_exp2f(__builtin_fmaf(s1[r], SC2, -nb)); lsum += s1[r]; }
        lsum += __shfl_xor(lsum, 32, 64);
        l_r = l_r * fct + lsum;
#pragma unroll
        for (int r = 0; r < 16; r++) { o0[r] *= fct; o1[r] *= fct; o2[r] *= fct; }

        // pack P into PV B-fragments: 16 cvt_pk + 8 permlane32_swap, zero LDS
        unsigned u0[2][4], u1[2][4];
#pragma unroll
        for (int a = 0; a < 4; a++) {
            u0[0][a] = cvtpk2(s0[4 * a + 0], s0[4 * a + 1]);
            u1[0][a] = cvtpk2(s0[4 * a + 2], s0[4 * a + 3]);
            u0[1][a] = cvtpk2(s1[4 * a + 0], s1[4 * a + 1]);
            u1[1][a] = cvtpk2(s1[4 * a + 2], s1[4 * a + 3]);
        }
#pragma unroll
        for (int kb2 = 0; kb2 < 2; kb2++)
#pragma unroll
            for (int a0 = 0; a0 < 4; a0 += 2) {
                plswap(u0[kb2][a0], u0[kb2][a0 + 1]);
                plswap(u1[kb2][a0], u1[kb2][a0 + 1]);
            }

        // O^T += V^T P : A = V^T[d][key] from LDS, B = P[key][q] from regs
#pragma unroll
        for (int t2 = 0; t2 < 4; t2++) {
            int kb2 = t2 >> 1, a0 = (t2 & 1) * 2;
            union { unsigned u[4]; bf16x8 v; } pf;
            pf.u[0] = u0[kb2][a0];     pf.u[1] = u1[kb2][a0];
            pf.u[2] = u0[kb2][a0 + 1]; pf.u[3] = u1[kb2][a0 + 1];
            int ch = kh * 8 + 2 * t2 + hi;
            int rv0 = lq, rv1 = 32 + lq, rv2 = 64 + lq;
            bf16x8 va0 = *(const bf16x8*)&Vl[cur][rv0 * 128 + ((ch ^ (rv0 & 15)) << 3)];
            bf16x8 va1 = *(const bf16x8*)&Vl[cur][rv1 * 128 + ((ch ^ (rv1 & 15)) << 3)];
            bf16x8 va2 = *(const bf16x8*)&Vl[cur][rv2 * 128 + ((ch ^ (rv2 & 15)) << 3)];
            o0 = __builtin_amdgcn_mfma_f32_32x32x16_bf16(va0, pf.v, o0, 0, 0, 0);
            o1 = __builtin_amdgcn_mfma_f32_32x32x16_bf16(va1, pf.v, o1, 0, 0, 0);
            o2 = __builtin_amdgcn_mfma_f32_32x32x16_bf16(va2, pf.v, o2, 0, 0, 0);
        }

        // write next tile to the other buffer, one barrier per tile
        if (kt < 31) {
            int nxt = cur ^ 1;
#pragma unroll
            for (int i = 0; i < 3; i++) {
                int c = i * 512 + tid;
                int row = c / 12, ch = c - row * 12;
                *(bf16x8*)&Kl[nxt][row * 128 + ((ch ^ (row & 15)) << 3)] = gk[i];
            }
#pragma unroll
            for (int i = 0; i < 3; i++) {
                int c = i * 512 + tid;
                int row = c >> 4, ch = c & 15;
                *(bf16x8*)&Vl[nxt][row * 128 + ((ch ^ (row & 15)) << 3)] = gv[i];
            }
        }
        __syncthreads();
    }

    // ---- combine key-half partials (wave pair wq: kh=0 with kh=1) via LDS ----
    float* xc = (float*)&Kl[0][0];
    float* rg = xc + (size_t)(wq * 64 + lane) * 52;
    if (kh == 1) {
#pragma unroll
        for (int r = 0; r < 16; r++) rg[r] = o0[r];
#pragma unroll
        for (int r = 0; r < 16; r++) rg[16 + r] = o1[r];
#pragma unroll
        for (int r = 0; r < 16; r++) rg[32 + r] = o2[r];
        rg[48] = m_r; rg[49] = l_r;
    }
    __syncthreads();
    if (kh == 0) {
        float m1 = rg[48], l1 = rg[49];
        float m12 = fmaxf(m_r, m1);
        float f0 = __builtin_amdgcn_exp2f((m_r - m12) * SC2);
        float f1 = __builtin_amdgcn_exp2f((m1 - m12) * SC2);
        float inv = 1.f / (l_r * f0 + l1 * f1);
        int token = q0 + wq * 32 + lq;
#pragma unroll
        for (int db = 0; db < 3; db++) {
#pragma unroll
            for (int r = 0; r < 16; r++) {
                int d = db * 32 + (r & 3) + 8 * (r >> 2) + 4 * hi;
                if (d < HD) {
                    float own = (db == 0) ? o0[r] : (db == 1) ? o1[r] : o2[r];
                    float val = (own * f0 + rg[db * 16 + r] * f1) * inv;
                    unsigned short hb = f2bf(val);
                    float lo = val - bf2f(hb);
                    size_t a = (size_t)token * KP + head * HD + d;
                    ahi[a] = hb; alo[a] = f2bf(lo);
                }
            }
        }
    }
}

// ---------------- proj GEMM (split-precision) ----------------
__launch_bounds__(256)
__global__ void k_gemm_proj(const unsigned short* __restrict__ Ahi_, const unsigned short* __restrict__ Alo_,
                            const unsigned short* __restrict__ Whi_, const unsigned short* __restrict__ Wlo_,
                            const float* __restrict__ bias, float* __restrict__ out) {
    constexpr int BM = 128, BN = 32, LDA = 40, LDB = 40;
    __shared__ unsigned short Ah[BM * LDA], Alw[BM * LDA], Bh[BN * LDB], Blw[BN * LDB];
    int tid = threadIdx.x, lane = tid & 63, wid = tid >> 6;
    int m0 = blockIdx.x * BM, n0 = blockIdx.y * BN;
    int wm = wid * 32;
    f32x4 acc[2][2] = {};
    for (int k0 = 0; k0 < KP; k0 += 32) {
        __syncthreads();
#pragma unroll
        for (int i = 0; i < 2; i++) {
            int c = i * 256 + tid;
            int row = c >> 2, kc = (c & 3) * 8;
            *(bf16x8*)&Ah[row * LDA + kc]  = *(const bf16x8*)&Ahi_[(size_t)(m0 + row) * KP + k0 + kc];
            *(bf16x8*)&Alw[row * LDA + kc] = *(const bf16x8*)&Alo_[(size_t)(m0 + row) * KP + k0 + kc];
        }
        if (tid < 128) {
            int row = tid >> 2, kc = (tid & 3) * 8;
            *(bf16x8*)&Bh[row * LDB + kc]  = *(const bf16x8*)&Whi_[(size_t)(n0 + row) * KP + k0 + kc];
            *(bf16x8*)&Blw[row * LDB + kc] = *(const bf16x8*)&Wlo_[(size_t)(n0 + row) * KP + k0 + kc];
        }
        __syncthreads();
        int kk = (lane >> 4) * 8;
        bf16x8 ah[2], al[2], bh[2], bl[2];
#pragma unroll
        for (int mi = 0; mi < 2; mi++) {
            ah[mi] = *(const bf16x8*)&Ah[(wm + mi * 16 + (lane & 15)) * LDA + kk];
            al[mi] = *(const bf16x8*)&Alw[(wm + mi * 16 + (lane & 15)) * LDA + kk];
        }
#pragma unroll
        for (int ni = 0; ni < 2; ni++) {
            bh[ni] = *(const bf16x8*)&Bh[(ni * 16 + (lane & 15)) * LDB + kk];
            bl[ni] = *(const bf16x8*)&Blw[(ni * 16 + (lane & 15)) * LDB + kk];
        }
#pragma unroll
        for (int mi = 0; mi < 2; mi++)
#pragma unroll
            for (int ni = 0; ni < 2; ni++) {
                acc[mi][ni] = __builtin_amdgcn_mfma_f32_16x16x32_bf16(ah[mi], bh[ni], acc[mi][ni], 0, 0, 0);
                acc[mi][ni] = __builtin_amdgcn_mfma_f32_16x16x32_bf16(ah[mi], bl[ni], acc[mi][ni], 0, 0, 0);
                acc[mi][ni] = __builtin_amdgcn_mfma_f32_16x16x32_bf16(al[mi], bh[ni], acc[mi][ni], 0, 0, 0);
            }
    }
#pragma unroll
    for (int mi = 0; mi < 2; mi++)
#pragma unroll
        for (int ni = 0; ni < 2; ni++)
#pragma unroll
            for (int r = 0; r < 4; r++) {
                int row = m0 + wm + mi * 16 + (lane >> 4) * 4 + r;
                int col = n0 + ni * 16 + (lane & 15);
                if (col < C) out[(size_t)row * C + col] = acc[mi][ni][r] + bias[col];
            }
}

extern "C" void kernel_launch(void* const* d_in, const int* in_sizes, int n_in,
                              void* d_out, int out_size, void* d_ws, size_t ws_size,
                              hipStream_t stream) {
    const float* x      = (const float*)d_in[0];
    const float* w_qkv  = (const float*)d_in[1];
    const float* b_qkv  = (const float*)d_in[2];
    const float* w_proj = (const float*)d_in[3];
    const float* b_proj = (const float*)d_in[4];
    float* out = (float*)d_out;
    char* ws = (char*)d_ws;

    const size_t o_xb     = 0;                       // 4096*544*2  (aliased as ahi later)
    const size_t o_wqkvb  = o_xb     + 4456448;      // 1632*544*2
    const size_t o_whi    = o_wqkvb  + 1775616;      // 544*544*2
    const size_t o_wlo    = o_whi    + 591872;
    const size_t o_qkvtmp = o_wlo    + 591872;       // 4096*1632*2 (aliased as alo later)
    const size_t o_qbf    = o_qkvtmp + 13369344;     // 8*4096*96*2
    const size_t o_kbf    = o_qbf    + 6291456;
    const size_t o_vt     = o_kbf    + 6291456;      // 8*96*4096*2 = 6291456
    const size_t need     = o_vt + 6291456;
    if (ws_size < need) return;

    unsigned short* xb     = (unsigned short*)(ws + o_xb);
    unsigned short* wqkvb  = (unsigned short*)(ws + o_wqkvb);
    unsigned short* whi    = (unsigned short*)(ws + o_whi);
    unsigned short* wlo    = (unsigned short*)(ws + o_wlo);
    unsigned short* qkvtmp = (unsigned short*)(ws + o_qkvtmp);
    unsigned short* qbf    = (unsigned short*)(ws + o_qbf);
    unsigned short* kbf    = (unsigned short*)(ws + o_kbf);
    unsigned short* vt     = (unsigned short*)(ws + o_vt);
    unsigned short* ahi    = xb;
    unsigned short* alo    = qkvtmp;

    k_prep_x    <<<(N_TOK * KP + 255) / 256, 256, 0, stream>>>(x, xb);
    k_prep_wqkv <<<(NQKVP * KP + 255) / 256, 256, 0, stream>>>(w_qkv, wqkvb);
    k_prep_wproj<<<(KP * KP + 255) / 256, 256, 0, stream>>>(w_proj, whi, wlo);
    k_gemm_qkv  <<<dim3(N_TOK / 128, NQKVP / 96), 256, 0, stream>>>(xb, wqkvb, b_qkv, qkvtmp);
    k_scatter_qk<<<(NH * N_TOK * HDP + 255) / 256, 256, 0, stream>>>(qkvtmp, qbf, kbf);
    k_transpose_v<<<dim3(N_TOK / 64, NH), 256, 0, stream>>>(qkvtmp, vt);
    k_zero_pads <<<(N_TOK * (KP - C) + 255) / 256, 256, 0, stream>>>(ahi, alo);
    k_attn      <<<dim3(256), 512, 0, stream>>>(qbf, kbf, vt, ahi, alo);
    k_gemm_proj <<<dim3(N_TOK / 128, KP / 32), 256, 0, stream>>>(ahi, alo, whi, wlo, b_proj, out);
}

// Round 4
// 124.088 us; speedup vs baseline: 1.7833x; 1.1868x over previous
//
#include <hip/hip_runtime.h>

typedef __attribute__((ext_vector_type(8))) short bf16x8;
typedef __attribute__((ext_vector_type(4))) float f32x4;
typedef __attribute__((ext_vector_type(16))) float f32x16;

#define DEV __device__ __forceinline__

static constexpr int N_TOK = 4096;
static constexpr int C     = 528;
static constexpr int NH    = 8;
static constexpr int HD    = 66;
static constexpr int HDP   = 96;    // q/k head-dim padded
static constexpr int VD96  = 96;    // v head-dim padded to 96
static constexpr int KP    = 544;   // GEMM K padded 528->544 (17*32)
static constexpr int NQKV  = 1584;
static constexpr int NQKVP = 1632;  // 17*96

DEV unsigned short f2bf(float f) {
    unsigned int u = __float_as_uint(f);
    u = (u + 0x7fffu + ((u >> 16) & 1u)) >> 16;
    return (unsigned short)u;
}
DEV float bf2f(unsigned short h) { return __uint_as_float(((unsigned int)h) << 16); }
DEV unsigned cvtpk2(float a, float b) {
    unsigned r;
    asm("v_cvt_pk_bf16_f32 %0, %1, %2" : "=v"(r) : "v"(a), "v"(b));
    return r;
}
DEV void plswap(unsigned &a, unsigned &b) {
    asm volatile("v_permlane32_swap_b32 %0, %1" : "+v"(a), "+v"(b));
}

// ---------------- fused prep: xb, wqkvb, whi/wlo (pads zeroed on W side) ----------------
__global__ void k_prep_all(const float* __restrict__ x, const float* __restrict__ w_qkv,
                           const float* __restrict__ w_proj,
                           unsigned short* __restrict__ xb, unsigned short* __restrict__ wqkvb,
                           unsigned short* __restrict__ whi, unsigned short* __restrict__ wlo) {
    const int T0 = N_TOK * KP;          // xb
    const int T1 = T0 + NQKVP * KP;     // wqkvb
    const int T2 = T1 + KP * KP;        // whi+wlo
    for (int idx = blockIdx.x * 256 + threadIdx.x; idx < T2; idx += gridDim.x * 256) {
        if (idx < T0) {
            int n = idx / KP, k = idx - n * KP;
            xb[idx] = (k < C) ? f2bf(x[n * C + k]) : (unsigned short)0;
        } else if (idx < T1) {
            int j = idx - T0;
            int n = j / KP, k = j - n * KP;
            wqkvb[j] = (n < NQKV && k < C) ? f2bf(w_qkv[n * C + k]) : (unsigned short)0;
        } else {
            int j = idx - T1;
            int n = j / KP, k = j - n * KP;
            unsigned short hi = 0, lo = 0;
            if (n < C && k < C) {
                float v = w_proj[n * C + k];
                hi = f2bf(v);
                lo = f2bf(v - bf2f(hi));
            }
            whi[j] = hi; wlo[j] = lo;
        }
    }
}

// ---------------- QKV GEMM (double-buffered, 1 barrier/step) ----------------
__launch_bounds__(256)
__global__ void k_gemm_qkv(const unsigned short* __restrict__ A,
                           const unsigned short* __restrict__ B,
                           const float* __restrict__ bias,
                           unsigned short* __restrict__ Cout) {
    constexpr int LDA = 40;
    __shared__ unsigned short Al[2][128 * LDA];
    __shared__ unsigned short Bl[2][96 * LDA];
    int tid = threadIdx.x, lane = tid & 63, wid = tid >> 6;
    int m0 = blockIdx.x * 128, n0 = blockIdx.y * 96;
    int wm = (wid >> 1) * 64, wn = (wid & 1) * 48;
    int arow0 = tid >> 2, arow1 = (256 + tid) >> 2, akc = (tid & 3) * 8;
    bool bhave = tid < 128;
    int brow1 = (256 + tid) >> 2;   // 64..95 for tid<128
    f32x4 acc[4][3] = {};
    bf16x8 ra0, ra1, rb0, rb1;

    // prologue: tile 0
    ra0 = *(const bf16x8*)&A[(size_t)(m0 + arow0) * KP + akc];
    ra1 = *(const bf16x8*)&A[(size_t)(m0 + arow1) * KP + akc];
    rb0 = *(const bf16x8*)&B[(size_t)(n0 + arow0) * KP + akc];
    if (bhave) rb1 = *(const bf16x8*)&B[(size_t)(n0 + brow1) * KP + akc];
    *(bf16x8*)&Al[0][arow0 * LDA + akc] = ra0;
    *(bf16x8*)&Al[0][arow1 * LDA + akc] = ra1;
    *(bf16x8*)&Bl[0][arow0 * LDA + akc] = rb0;
    if (bhave) *(bf16x8*)&Bl[0][brow1 * LDA + akc] = rb1;
    __syncthreads();

    int kk = (lane >> 4) * 8, cc = lane & 15;
    for (int kt = 0; kt < 17; kt++) {
        int cur = kt & 1;
        if (kt < 16) {
            int k0 = (kt + 1) * 32;
            ra0 = *(const bf16x8*)&A[(size_t)(m0 + arow0) * KP + k0 + akc];
            ra1 = *(const bf16x8*)&A[(size_t)(m0 + arow1) * KP + k0 + akc];
            rb0 = *(const bf16x8*)&B[(size_t)(n0 + arow0) * KP + k0 + akc];
            if (bhave) rb1 = *(const bf16x8*)&B[(size_t)(n0 + brow1) * KP + k0 + akc];
        }
        bf16x8 af[4], bfr[3];
#pragma unroll
        for (int mi = 0; mi < 4; mi++) af[mi] = *(const bf16x8*)&Al[cur][(wm + mi * 16 + cc) * LDA + kk];
#pragma unroll
        for (int ni = 0; ni < 3; ni++) bfr[ni] = *(const bf16x8*)&Bl[cur][(wn + ni * 16 + cc) * LDA + kk];
#pragma unroll
        for (int mi = 0; mi < 4; mi++)
#pragma unroll
            for (int ni = 0; ni < 3; ni++)
                acc[mi][ni] = __builtin_amdgcn_mfma_f32_16x16x32_bf16(af[mi], bfr[ni], acc[mi][ni], 0, 0, 0);
        if (kt < 16) {
            int nxt = cur ^ 1;
            *(bf16x8*)&Al[nxt][arow0 * LDA + akc] = ra0;
            *(bf16x8*)&Al[nxt][arow1 * LDA + akc] = ra1;
            *(bf16x8*)&Bl[nxt][arow0 * LDA + akc] = rb0;
            if (bhave) *(bf16x8*)&Bl[nxt][brow1 * LDA + akc] = rb1;
        }
        __syncthreads();
    }
#pragma unroll
    for (int mi = 0; mi < 4; mi++)
#pragma unroll
        for (int ni = 0; ni < 3; ni++)
#pragma unroll
            for (int r = 0; r < 4; r++) {
                int row = m0 + wm + mi * 16 + (lane >> 4) * 4 + r;
                int col = n0 + wn + ni * 16 + cc;
                float v = acc[mi][ni][r] + (col < NQKV ? bias[col] : 0.f);
                Cout[(size_t)row * NQKVP + col] = f2bf(v);
            }
}

// ---------------- fused reshape: z=0 scatter q/k, z=1 transpose v ----------------
__global__ void k_reshape(const unsigned short* __restrict__ T,
                          unsigned short* __restrict__ qb, unsigned short* __restrict__ kbuf,
                          unsigned short* __restrict__ vt) {
    int h = blockIdx.y, n0 = blockIdx.x * 64, tid = threadIdx.x;
    if (blockIdx.z == 0) {
#pragma unroll
        for (int i = 0; i < 24; i++) {
            int idx = i * 256 + tid;
            int ni = idx / 96, d = idx - ni * 96;
            unsigned short zq = 0, zk = 0;
            if (d < HD) {
                zq = T[(size_t)(n0 + ni) * NQKVP + h * HD + d];
                zk = T[(size_t)(n0 + ni) * NQKVP + C + h * HD + d];
            }
            size_t a = ((size_t)h * N_TOK + n0 + ni) * HDP + d;
            qb[a] = zq; kbuf[a] = zk;
        }
    } else {
        __shared__ unsigned short lt[64 * 104];
#pragma unroll
        for (int i = 0; i < 24; i++) {
            int idx = i * 256 + tid;
            int ni = idx / 96, d = idx - ni * 96;
            unsigned short v = 0;
            if (d < HD) v = T[(size_t)(n0 + ni) * NQKVP + 2 * C + h * HD + d];
            lt[ni * 104 + d] = v;
        }
        __syncthreads();
#pragma unroll
        for (int i = 0; i < 24; i++) {
            int idx = i * 256 + tid;
            int d = idx >> 6, ni = idx & 63;
            vt[((size_t)h * VD96 + d) * N_TOK + n0 + ni] = lt[ni * 104 + d];
        }
    }
}

// ---------------- flash attention: swapped QK^T, 32x32 MFMA, in-register P, defer-rescale ----------------
__launch_bounds__(512, 2)
__global__ void k_attn(const unsigned short* __restrict__ qb,
                       const unsigned short* __restrict__ kb,
                       const unsigned short* __restrict__ vt,
                       unsigned short* __restrict__ ahi,
                       unsigned short* __restrict__ alo) {
    __shared__ __align__(16) unsigned short Kl[2][128 * 128];
    __shared__ __align__(16) unsigned short Vl[2][96 * 128];
    int tid = threadIdx.x, lane = tid & 63, wid = tid >> 6;
    int wq = wid & 3, kh = wid >> 2;
    int hi = lane >> 5, lq = lane & 31;
    int bid = blockIdx.x;
    int head = bid & 7;
    int q0 = (bid >> 3) * 128;
    const float SC2 = 0.12309149097933274f * 1.4426950408889634f;

    bf16x8 aq[6];
    {
        const unsigned short* qrow = qb + ((size_t)head * N_TOK + q0 + wq * 32 + lq) * HDP + hi * 8;
#pragma unroll
        for (int t = 0; t < 6; t++) aq[t] = *(const bf16x8*)&qrow[t * 16];
    }
    f32x16 o0 = {}, o1 = {}, o2 = {};
    float m_r = -3e38f, l_r = 0.f;

    const unsigned short* kg = kb + (size_t)head * N_TOK * HDP;
    const unsigned short* vg = vt + (size_t)head * VD96 * N_TOK;

#pragma unroll
    for (int i = 0; i < 3; i++) {
        int c = i * 512 + tid;
        int row = c / 12, ch = c - row * 12;
        *(bf16x8*)&Kl[0][row * 128 + ((ch ^ (row & 15)) << 3)] =
            *(const bf16x8*)&kg[(size_t)row * HDP + ch * 8];
    }
#pragma unroll
    for (int i = 0; i < 3; i++) {
        int c = i * 512 + tid;
        int row = c >> 4, ch = c & 15;
        *(bf16x8*)&Vl[0][row * 128 + ((ch ^ (row & 15)) << 3)] =
            *(const bf16x8*)&vg[(size_t)row * N_TOK + ch * 8];
    }
    __syncthreads();

    for (int kt = 0; kt < 32; kt++) {
        int cur = kt & 1;
        bf16x8 gk[3], gv[3];
        if (kt < 31) {
            int n1 = (kt + 1) * 128;
#pragma unroll
            for (int i = 0; i < 3; i++) {
                int c = i * 512 + tid;
                int row = c / 12, ch = c - row * 12;
                gk[i] = *(const bf16x8*)&kg[(size_t)(n1 + row) * HDP + ch * 8];
            }
#pragma unroll
            for (int i = 0; i < 3; i++) {
                int c = i * 512 + tid;
                int row = c >> 4, ch = c & 15;
                gv[i] = *(const bf16x8*)&vg[(size_t)row * N_TOK + n1 + ch * 8];
            }
        }

        f32x16 s0 = {}, s1 = {};
        {
            int r0 = kh * 64 + lq, r1 = r0 + 32;
#pragma unroll
            for (int t = 0; t < 6; t++) {
                bf16x8 ka0 = *(const bf16x8*)&Kl[cur][r0 * 128 + (((2 * t + hi) ^ (r0 & 15)) << 3)];
                bf16x8 ka1 = *(const bf16x8*)&Kl[cur][r1 * 128 + (((2 * t + hi) ^ (r1 & 15)) << 3)];
                s0 = __builtin_amdgcn_mfma_f32_32x32x16_bf16(ka0, aq[t], s0, 0, 0, 0);
                s1 = __builtin_amdgcn_mfma_f32_32x32x16_bf16(ka1, aq[t], s1, 0, 0, 0);
            }
        }

        // online softmax with T13 defer-rescale
        float mx = s0[0];
#pragma unroll
        for (int r = 1; r < 16; r++) mx = fmaxf(mx, s0[r]);
#pragma unroll
        for (int r = 0; r < 16; r++) mx = fmaxf(mx, s1[r]);
        mx = fmaxf(mx, __shfl_xor(mx, 32, 64));
        if (!__all((mx - m_r) * SC2 <= 8.f)) {
            float mnew = fmaxf(m_r, mx);
            float fct = __builtin_amdgcn_exp2f((m_r - mnew) * SC2);
            m_r = mnew;
            l_r *= fct;
#pragma unroll
            for (int r = 0; r < 16; r++) { o0[r] *= fct; o1[r] *= fct; o2[r] *= fct; }
        }
        float nb = m_r * SC2;
        float lsum = 0.f;
#pragma unroll
        for (int r = 0; r < 16; r++) { s0[r] = __builtin_amdgcn_exp2f(__builtin_fmaf(s0[r], SC2, -nb)); lsum += s0[r]; }
#pragma unroll
        for (int r = 0; r < 16; r++) { s1[r] = __builtin_amdgcn_exp2f(__builtin_fmaf(s1[r], SC2, -nb)); lsum += s1[r]; }
        lsum += __shfl_xor(lsum, 32, 64);
        l_r += lsum;

        unsigned u0[2][4], u1[2][4];
#pragma unroll
        for (int a = 0; a < 4; a++) {
            u0[0][a] = cvtpk2(s0[4 * a + 0], s0[4 * a + 1]);
            u1[0][a] = cvtpk2(s0[4 * a + 2], s0[4 * a + 3]);
            u0[1][a] = cvtpk2(s1[4 * a + 0], s1[4 * a + 1]);
            u1[1][a] = cvtpk2(s1[4 * a + 2], s1[4 * a + 3]);
        }
#pragma unroll
        for (int kb2 = 0; kb2 < 2; kb2++)
#pragma unroll
            for (int a0 = 0; a0 < 4; a0 += 2) {
                plswap(u0[kb2][a0], u0[kb2][a0 + 1]);
                plswap(u1[kb2][a0], u1[kb2][a0 + 1]);
            }

#pragma unroll
        for (int t2 = 0; t2 < 4; t2++) {
            int kb2 = t2 >> 1, a0 = (t2 & 1) * 2;
            union { unsigned u[4]; bf16x8 v; } pf;
            pf.u[0] = u0[kb2][a0];     pf.u[1] = u1[kb2][a0];
            pf.u[2] = u0[kb2][a0 + 1]; pf.u[3] = u1[kb2][a0 + 1];
            int ch = kh * 8 + 2 * t2 + hi;
            int rv0 = lq, rv1 = 32 + lq, rv2 = 64 + lq;
            bf16x8 va0 = *(const bf16x8*)&Vl[cur][rv0 * 128 + ((ch ^ (rv0 & 15)) << 3)];
            bf16x8 va1 = *(const bf16x8*)&Vl[cur][rv1 * 128 + ((ch ^ (rv1 & 15)) << 3)];
            bf16x8 va2 = *(const bf16x8*)&Vl[cur][rv2 * 128 + ((ch ^ (rv2 & 15)) << 3)];
            o0 = __builtin_amdgcn_mfma_f32_32x32x16_bf16(va0, pf.v, o0, 0, 0, 0);
            o1 = __builtin_amdgcn_mfma_f32_32x32x16_bf16(va1, pf.v, o1, 0, 0, 0);
            o2 = __builtin_amdgcn_mfma_f32_32x32x16_bf16(va2, pf.v, o2, 0, 0, 0);
        }

        if (kt < 31) {
            int nxt = cur ^ 1;
#pragma unroll
            for (int i = 0; i < 3; i++) {
                int c = i * 512 + tid;
                int row = c / 12, ch = c - row * 12;
                *(bf16x8*)&Kl[nxt][row * 128 + ((ch ^ (row & 15)) << 3)] = gk[i];
            }
#pragma unroll
            for (int i = 0; i < 3; i++) {
                int c = i * 512 + tid;
                int row = c >> 4, ch = c & 15;
                *(bf16x8*)&Vl[nxt][row * 128 + ((ch ^ (row & 15)) << 3)] = gv[i];
            }
        }
        __syncthreads();
    }

    float* xc = (float*)&Kl[0][0];
    float* rg = xc + (size_t)(wq * 64 + lane) * 52;
    if (kh == 1) {
#pragma unroll
        for (int r = 0; r < 16; r++) rg[r] = o0[r];
#pragma unroll
        for (int r = 0; r < 16; r++) rg[16 + r] = o1[r];
#pragma unroll
        for (int r = 0; r < 16; r++) rg[32 + r] = o2[r];
        rg[48] = m_r; rg[49] = l_r;
    }
    __syncthreads();
    if (kh == 0) {
        float m1 = rg[48], l1 = rg[49];
        float m12 = fmaxf(m_r, m1);
        float f0 = __builtin_amdgcn_exp2f((m_r - m12) * SC2);
        float f1 = __builtin_amdgcn_exp2f((m1 - m12) * SC2);
        float inv = 1.f / (l_r * f0 + l1 * f1);
        int token = q0 + wq * 32 + lq;
#pragma unroll
        for (int db = 0; db < 3; db++) {
#pragma unroll
            for (int r = 0; r < 16; r++) {
                int d = db * 32 + (r & 3) + 8 * (r >> 2) + 4 * hi;
                if (d < HD) {
                    float own = (db == 0) ? o0[r] : (db == 1) ? o1[r] : o2[r];
                    float val = (own * f0 + rg[db * 16 + r] * f1) * inv;
                    unsigned short hb = f2bf(val);
                    float lo = val - bf2f(hb);
                    size_t a = (size_t)token * KP + head * HD + d;
                    ahi[a] = hb; alo[a] = f2bf(lo);
                }
            }
        }
    }
}

// ---------------- proj GEMM (split-precision, BN=64, double-buffered) ----------------
__launch_bounds__(256)
__global__ void k_gemm_proj(const unsigned short* __restrict__ Ahi_, const unsigned short* __restrict__ Alo_,
                            const unsigned short* __restrict__ Whi_, const unsigned short* __restrict__ Wlo_,
                            const float* __restrict__ bias, float* __restrict__ out) {
    constexpr int LDA = 40;
    __shared__ unsigned short Ah[2][128 * LDA], Aw[2][128 * LDA];
    __shared__ unsigned short Bh[2][64 * LDA],  Bw[2][64 * LDA];
    int tid = threadIdx.x, lane = tid & 63, wid = tid >> 6;
    int m0 = blockIdx.x * 128, n0 = blockIdx.y * 64;
    int wm = wid * 32;
    int arow0 = tid >> 2, arow1 = (256 + tid) >> 2, akc = (tid & 3) * 8;
    bool bok = (n0 + arow0) < KP;   // B-row guard (rows beyond 544 only in last block... n0<=512, arow0<=63 -> max 575)
    f32x4 acc[2][4] = {};
    bf16x8 rah0, rah1, ral0, ral1, rbh, rbl;
    const bf16x8 zero8 = {};

    rah0 = *(const bf16x8*)&Ahi_[(size_t)(m0 + arow0) * KP + akc];
    rah1 = *(const bf16x8*)&Ahi_[(size_t)(m0 + arow1) * KP + akc];
    ral0 = *(const bf16x8*)&Alo_[(size_t)(m0 + arow0) * KP + akc];
    ral1 = *(const bf16x8*)&Alo_[(size_t)(m0 + arow1) * KP + akc];
    rbh = bok ? *(const bf16x8*)&Whi_[(size_t)(n0 + arow0) * KP + akc] : zero8;
    rbl = bok ? *(const bf16x8*)&Wlo_[(size_t)(n0 + arow0) * KP + akc] : zero8;
    *(bf16x8*)&Ah[0][arow0 * LDA + akc] = rah0;
    *(bf16x8*)&Ah[0][arow1 * LDA + akc] = rah1;
    *(bf16x8*)&Aw[0][arow0 * LDA + akc] = ral0;
    *(bf16x8*)&Aw[0][arow1 * LDA + akc] = ral1;
    *(bf16x8*)&Bh[0][arow0 * LDA + akc] = rbh;
    *(bf16x8*)&Bw[0][arow0 * LDA + akc] = rbl;
    __syncthreads();

    int kk = (lane >> 4) * 8, cc = lane & 15;
    for (int kt = 0; kt < 17; kt++) {
        int cur = kt & 1;
        if (kt < 16) {
            int k0 = (kt + 1) * 32;
            rah0 = *(const bf16x8*)&Ahi_[(size_t)(m0 + arow0) * KP + k0 + akc];
            rah1 = *(const bf16x8*)&Ahi_[(size_t)(m0 + arow1) * KP + k0 + akc];
            ral0 = *(const bf16x8*)&Alo_[(size_t)(m0 + arow0) * KP + k0 + akc];
            ral1 = *(const bf16x8*)&Alo_[(size_t)(m0 + arow1) * KP + k0 + akc];
            rbh = bok ? *(const bf16x8*)&Whi_[(size_t)(n0 + arow0) * KP + k0 + akc] : zero8;
            rbl = bok ? *(const bf16x8*)&Wlo_[(size_t)(n0 + arow0) * KP + k0 + akc] : zero8;
        }
        bf16x8 ah[2], al[2], bh[4], bl[4];
#pragma unroll
        for (int mi = 0; mi < 2; mi++) {
            ah[mi] = *(const bf16x8*)&Ah[cur][(wm + mi * 16 + cc) * LDA + kk];
            al[mi] = *(const bf16x8*)&Aw[cur][(wm + mi * 16 + cc) * LDA + kk];
        }
#pragma unroll
        for (int ni = 0; ni < 4; ni++) {
            bh[ni] = *(const bf16x8*)&Bh[cur][(ni * 16 + cc) * LDA + kk];
            bl[ni] = *(const bf16x8*)&Bw[cur][(ni * 16 + cc) * LDA + kk];
        }
#pragma unroll
        for (int mi = 0; mi < 2; mi++)
#pragma unroll
            for (int ni = 0; ni < 4; ni++) {
                acc[mi][ni] = __builtin_amdgcn_mfma_f32_16x16x32_bf16(ah[mi], bh[ni], acc[mi][ni], 0, 0, 0);
                acc[mi][ni] = __builtin_amdgcn_mfma_f32_16x16x32_bf16(ah[mi], bl[ni], acc[mi][ni], 0, 0, 0);
                acc[mi][ni] = __builtin_amdgcn_mfma_f32_16x16x32_bf16(al[mi], bh[ni], acc[mi][ni], 0, 0, 0);
            }
        if (kt < 16) {
            int nxt = cur ^ 1;
            *(bf16x8*)&Ah[nxt][arow0 * LDA + akc] = rah0;
            *(bf16x8*)&Ah[nxt][arow1 * LDA + akc] = rah1;
            *(bf16x8*)&Aw[nxt][arow0 * LDA + akc] = ral0;
            *(bf16x8*)&Aw[nxt][arow1 * LDA + akc] = ral1;
            *(bf16x8*)&Bh[nxt][arow0 * LDA + akc] = rbh;
            *(bf16x8*)&Bw[nxt][arow0 * LDA + akc] = rbl;
        }
        __syncthreads();
    }
#pragma unroll
    for (int mi = 0; mi < 2; mi++)
#pragma unroll
        for (int ni = 0; ni < 4; ni++)
#pragma unroll
            for (int r = 0; r < 4; r++) {
                int row = m0 + wm + mi * 16 + (lane >> 4) * 4 + r;
                int col = n0 + ni * 16 + cc;
                if (col < C) out[(size_t)row * C + col] = acc[mi][ni][r] + bias[col];
            }
}

extern "C" void kernel_launch(void* const* d_in, const int* in_sizes, int n_in,
                              void* d_out, int out_size, void* d_ws, size_t ws_size,
                              hipStream_t stream) {
    const float* x      = (const float*)d_in[0];
    const float* w_qkv  = (const float*)d_in[1];
    const float* b_qkv  = (const float*)d_in[2];
    const float* w_proj = (const float*)d_in[3];
    const float* b_proj = (const float*)d_in[4];
    float* out = (float*)d_out;
    char* ws = (char*)d_ws;

    const size_t o_xb     = 0;                       // 4096*544*2 (aliased as ahi later)
    const size_t o_wqkvb  = o_xb     + 4456448;      // 1632*544*2
    const size_t o_whi    = o_wqkvb  + 1775616;      // 544*544*2
    const size_t o_wlo    = o_whi    + 591872;
    const size_t o_qkvtmp = o_wlo    + 591872;       // 4096*1632*2 (aliased as alo later)
    const size_t o_qbf    = o_qkvtmp + 13369344;     // 8*4096*96*2
    const size_t o_kbf    = o_qbf    + 6291456;
    const size_t o_vt     = o_kbf    + 6291456;      // 8*96*4096*2
    const size_t need     = o_vt + 6291456;
    if (ws_size < need) return;

    unsigned short* xb     = (unsigned short*)(ws + o_xb);
    unsigned short* wqkvb  = (unsigned short*)(ws + o_wqkvb);
    unsigned short* whi    = (unsigned short*)(ws + o_whi);
    unsigned short* wlo    = (unsigned short*)(ws + o_wlo);
    unsigned short* qkvtmp = (unsigned short*)(ws + o_qkvtmp);
    unsigned short* qbf    = (unsigned short*)(ws + o_qbf);
    unsigned short* kbf    = (unsigned short*)(ws + o_kbf);
    unsigned short* vt     = (unsigned short*)(ws + o_vt);
    unsigned short* ahi    = xb;       // dead after k_gemm_qkv; A-pads (cols>=528) stay zero from prep
    unsigned short* alo    = qkvtmp;   // dead after k_reshape; pad garbage annihilated by zeroed W-pads

    k_prep_all  <<<2048, 256, 0, stream>>>(x, w_qkv, w_proj, xb, wqkvb, whi, wlo);
    k_gemm_qkv  <<<dim3(N_TOK / 128, NQKVP / 96), 256, 0, stream>>>(xb, wqkvb, b_qkv, qkvtmp);
    k_reshape   <<<dim3(N_TOK / 64, NH, 2), 256, 0, stream>>>(qkvtmp, qbf, kbf, vt);
    k_attn      <<<dim3(256), 512, 0, stream>>>(qbf, kbf, vt, ahi, alo);
    k_gemm_proj <<<dim3(N_TOK / 128, 9), 256, 0, stream>>>(ahi, alo, whi, wlo, b_proj, out);
}